// Round 1
// baseline (179.802 us; speedup 1.0000x reference)
//
#include <hip/hip_runtime.h>
#include <math.h>
#include <stdint.h>

#define NG 8
#define GS 2048
#define DM 512
#define NE 64
#define CAP 32
#define NROWS (NG * GS)                       // 16384 total rows (g,s)
#define COMBINE_ELEMS (33554432ull)           // 8*2048*64*32

// ---------------------------------------------------------------------------
// JAX Threefry-2x32 (partitionable path): bits[i] = o0 ^ o1 of
// threefry2x32(key=(0,42), x=(hi(i)=0, lo(i)=i)).
// ---------------------------------------------------------------------------
__device__ __forceinline__ void threefry2x32(uint32_t k0, uint32_t k1,
                                             uint32_t x0, uint32_t x1,
                                             uint32_t& o0, uint32_t& o1) {
  uint32_t ks[3] = {k0, k1, k0 ^ k1 ^ 0x1BD11BDAu};
  x0 += ks[0];
  x1 += ks[1];
  const uint32_t rot[2][4] = {{13u, 15u, 26u, 6u}, {17u, 29u, 16u, 24u}};
#pragma unroll
  for (int i = 0; i < 5; ++i) {
#pragma unroll
    for (int j = 0; j < 4; ++j) {
      uint32_t r = rot[i & 1][j];
      x0 += x1;
      x1 = (x1 << r) | (x1 >> (32u - r));
      x1 ^= x0;
    }
    x0 += ks[(i + 1) % 3];
    x1 += ks[(i + 2) % 3] + (uint32_t)(i + 1);
  }
  o0 = x0;
  o1 = x1;
}

// XLA ErfInv (f32), Giles polynomial — constants bit-match xla math.cc.
__device__ __forceinline__ float erfinv_xla(float x) {
  float w = -log1pf(-x * x);
  float p;
  if (w < 5.0f) {
    w = w - 2.5f;
    p = 2.81022636e-08f;
    p = __fmaf_rn(p, w, 3.43273939e-07f);
    p = __fmaf_rn(p, w, -3.5233877e-06f);
    p = __fmaf_rn(p, w, -4.39150654e-06f);
    p = __fmaf_rn(p, w, 0.00021858087f);
    p = __fmaf_rn(p, w, -0.00125372503f);
    p = __fmaf_rn(p, w, -0.00417768164f);
    p = __fmaf_rn(p, w, 0.246640727f);
    p = __fmaf_rn(p, w, 1.50140941f);
  } else {
    w = sqrtf(w) - 3.0f;
    p = -0.000200214257f;
    p = __fmaf_rn(p, w, 0.000100950558f);
    p = __fmaf_rn(p, w, 0.00134934322f);
    p = __fmaf_rn(p, w, -0.00367342844f);
    p = __fmaf_rn(p, w, 0.00573950773f);
    p = __fmaf_rn(p, w, -0.0076224613f);
    p = __fmaf_rn(p, w, 0.00943887047f);
    p = __fmaf_rn(p, w, 1.00167406f);
    p = __fmaf_rn(p, w, 2.83297682f);
  }
  return p * x;
}

// jax.random.normal(key(42), ...) element at flat index idx (f32).
__device__ __forceinline__ float jax_normal(uint32_t idx) {
  uint32_t o0, o1;
  threefry2x32(0u, 42u, 0u, idx, o0, o1);
  uint32_t bits = o0 ^ o1;
  // uniform in [lo, 1) with lo = nextafter(-1, 0):
  float f = __uint_as_float((bits >> 9) | 0x3f800000u) - 1.0f;  // [0,1)
  const float lo = __uint_as_float(0xBF7FFFFFu);                // -0.99999994
  float v = fmaxf(lo, f * 2.0f + lo);  // (hi - lo) rounds to exactly 2.0f
  return __uint_as_float(0x3FB504F3u) * erfinv_xla(v);  // sqrt(2)_f32 * erfinv
}

// ---------------------------------------------------------------------------
// Kernel 0: zero the whole output (harness poisons with 0xAA before timing).
// ---------------------------------------------------------------------------
__global__ void zero_kernel(float4* __restrict__ p, int n4) {
  int i = blockIdx.x * blockDim.x + threadIdx.x;
  int stride = gridDim.x * blockDim.x;
  for (; i < n4; i += stride) p[i] = make_float4(0.f, 0.f, 0.f, 0.f);
}

// ---------------------------------------------------------------------------
// Kernel 1: fused gating GEMM (fp64 accum) + threefry noise + fp64 softmax.
// Block = 256 threads = 4 waves; each block does 16 rows; lane = expert.
// Wave q owns rows {q, q+4, q+8, q+12} of the 16-row tile (one row per acc).
// ---------------------------------------------------------------------------
#define RPB 16
__global__ __launch_bounds__(256) void gate_kernel(
    const float* __restrict__ x,   // (NROWS, 512)
    const float* __restrict__ Wt,  // (512, 64)
    float* __restrict__ gates) {   // (NROWS, 64)
  __shared__ float xs[RPB * DM];  // 32 KB
  const int e = threadIdx.x & 63;
  const int q = threadIdx.x >> 6;  // 0..3
  const int row0 = blockIdx.x * RPB;

  // stage x tile (coalesced float4)
  const float4* src = (const float4*)(x + (size_t)row0 * DM);
  float4* dst = (float4*)xs;
  for (int i = threadIdx.x; i < RPB * (DM / 4); i += 256) dst[i] = src[i];
  __syncthreads();

  double acc[4] = {0.0, 0.0, 0.0, 0.0};
  for (int d = 0; d < DM; ++d) {
    double w = (double)Wt[d * NE + e];
#pragma unroll
    for (int j = 0; j < 4; ++j)
      acc[j] += (double)xs[(q + 4 * j) * DM + d] * w;
  }

#pragma unroll
  for (int j = 0; j < 4; ++j) {
    const int row = row0 + q + 4 * j;
    float logit = (float)acc[j];
    // noise = (NOISE_STD/NUM_EXPERTS) * normal; 1/64 is exact in f32
    float noised = logit + 0.015625f * jax_normal((uint32_t)(row * NE + e));
    // fp64 softmax across the 64 lanes (one expert per lane)
    double v = (double)noised;
    double m = v;
#pragma unroll
    for (int off = 32; off; off >>= 1) m = fmax(m, __shfl_xor(m, off, 64));
    double ex = exp(v - m);
    double s = ex;
#pragma unroll
    for (int off = 32; off; off >>= 1) s += __shfl_xor(s, off, 64);
    gates[(size_t)row * NE + e] = (float)(ex / s);
  }
}

// ---------------------------------------------------------------------------
// Kernel 2: per-(group, expert) top-32 (value desc, index asc on ties) and
// sparse scatter into combine/dispatch.
// ---------------------------------------------------------------------------
__global__ __launch_bounds__(256) void topk_kernel(
    const float* __restrict__ gates,  // (NROWS, 64)
    float* __restrict__ out) {        // combine ++ dispatch
  const int ge = blockIdx.x;  // 0..511
  const int g = ge >> 6;
  const int e = ge & 63;
  __shared__ float vals[GS];
  __shared__ float rv[256];
  __shared__ int ri[256];
  const int t = threadIdx.x;

  for (int s = t; s < GS; s += 256)
    vals[s] = gates[((size_t)(g * GS + s)) * NE + e];
  __syncthreads();

  float* combine = out;                          // (G,S,E,C)
  float* dispatch = out + COMBINE_ELEMS;         // (G,E,C,S)

  for (int c = 0; c < CAP; ++c) {
    float bv = -INFINITY;
    int bi = 0x7fffffff;
    for (int s = t; s < GS; s += 256) {
      float v = vals[s];
      if (v > bv || (v == bv && s < bi)) { bv = v; bi = s; }
    }
    rv[t] = bv;
    ri[t] = bi;
    __syncthreads();
    for (int off = 128; off > 0; off >>= 1) {
      if (t < off) {
        float ov = rv[t + off];
        int oi = ri[t + off];
        if (ov > rv[t] || (ov == rv[t] && oi < ri[t])) { rv[t] = ov; ri[t] = oi; }
      }
      __syncthreads();
    }
    if (t == 0) {
      const int s_sel = ri[0];
      const float v_sel = rv[0];
      combine[(((size_t)(g * GS + s_sel)) * NE + e) * CAP + c] = v_sel;
      dispatch[(((size_t)(g * NE + e)) * CAP + c) * GS + s_sel] = 1.0f;
      vals[s_sel] = -INFINITY;
    }
    __syncthreads();
  }
}

extern "C" void kernel_launch(void* const* d_in, const int* in_sizes, int n_in,
                              void* d_out, int out_size, void* d_ws,
                              size_t ws_size, hipStream_t stream) {
  (void)in_sizes; (void)n_in; (void)ws_size;
  const float* x = (const float*)d_in[0];   // (8,2048,512) f32
  const float* Wt = (const float*)d_in[1];  // (512,64) f32
  float* out = (float*)d_out;
  float* gates = (float*)d_ws;              // 16384*64 f32 = 4 MB scratch

  // 1) zero the 256 MB output
  int n4 = out_size / 4;
  zero_kernel<<<2048, 256, 0, stream>>>((float4*)out, n4);
  // 2) gates
  gate_kernel<<<NROWS / RPB, 256, 0, stream>>>(x, Wt, gates);
  // 3) top-32 per (g,e) + scatter
  topk_kernel<<<NG * NE, 256, 0, stream>>>(gates, out);
}

// Round 3
// 162.197 us; speedup vs baseline: 1.1085x; 1.1085x over previous
//
#include <hip/hip_runtime.h>
#include <math.h>
#include <stdint.h>

#define NG 8
#define GS 2048
#define DM 512
#define NE 64
#define CAP 32
#define NROWS (NG * GS)                       // 16384 total rows (g,s)
#define COMBINE_ELEMS (33554432ull)           // 8*2048*64*32

typedef float f32x4 __attribute__((ext_vector_type(4)));

// ---------------------------------------------------------------------------
// JAX Threefry-2x32 (partitionable path): bits[i] = o0 ^ o1 of
// threefry2x32(key=(0,42), x=(hi(i)=0, lo(i)=i)).   [verified: round 1 pass]
// ---------------------------------------------------------------------------
__device__ __forceinline__ void threefry2x32(uint32_t k0, uint32_t k1,
                                             uint32_t x0, uint32_t x1,
                                             uint32_t& o0, uint32_t& o1) {
  uint32_t ks[3] = {k0, k1, k0 ^ k1 ^ 0x1BD11BDAu};
  x0 += ks[0];
  x1 += ks[1];
  const uint32_t rot[2][4] = {{13u, 15u, 26u, 6u}, {17u, 29u, 16u, 24u}};
#pragma unroll
  for (int i = 0; i < 5; ++i) {
#pragma unroll
    for (int j = 0; j < 4; ++j) {
      uint32_t r = rot[i & 1][j];
      x0 += x1;
      x1 = (x1 << r) | (x1 >> (32u - r));
      x1 ^= x0;
    }
    x0 += ks[(i + 1) % 3];
    x1 += ks[(i + 2) % 3] + (uint32_t)(i + 1);
  }
  o0 = x0;
  o1 = x1;
}

// XLA ErfInv (f32), Giles polynomial — constants bit-match xla math.cc.
__device__ __forceinline__ float erfinv_xla(float x) {
  float w = -log1pf(-x * x);
  float p;
  if (w < 5.0f) {
    w = w - 2.5f;
    p = 2.81022636e-08f;
    p = __fmaf_rn(p, w, 3.43273939e-07f);
    p = __fmaf_rn(p, w, -3.5233877e-06f);
    p = __fmaf_rn(p, w, -4.39150654e-06f);
    p = __fmaf_rn(p, w, 0.00021858087f);
    p = __fmaf_rn(p, w, -0.00125372503f);
    p = __fmaf_rn(p, w, -0.00417768164f);
    p = __fmaf_rn(p, w, 0.246640727f);
    p = __fmaf_rn(p, w, 1.50140941f);
  } else {
    w = sqrtf(w) - 3.0f;
    p = -0.000200214257f;
    p = __fmaf_rn(p, w, 0.000100950558f);
    p = __fmaf_rn(p, w, 0.00134934322f);
    p = __fmaf_rn(p, w, -0.00367342844f);
    p = __fmaf_rn(p, w, 0.00573950773f);
    p = __fmaf_rn(p, w, -0.0076224613f);
    p = __fmaf_rn(p, w, 0.00943887047f);
    p = __fmaf_rn(p, w, 1.00167406f);
    p = __fmaf_rn(p, w, 2.83297682f);
  }
  return p * x;
}

__device__ __forceinline__ float jax_normal(uint32_t idx) {
  uint32_t o0, o1;
  threefry2x32(0u, 42u, 0u, idx, o0, o1);
  uint32_t bits = o0 ^ o1;
  float f = __uint_as_float((bits >> 9) | 0x3f800000u) - 1.0f;  // [0,1)
  const float lo = __uint_as_float(0xBF7FFFFFu);                // -0.99999994
  float v = fmaxf(lo, f * 2.0f + lo);
  return __uint_as_float(0x3FB504F3u) * erfinv_xla(v);  // sqrt(2)_f32 * erfinv
}

// ---------------------------------------------------------------------------
// Kernel 0: zero the 256 MB output (harness poisons with 0xAA before timing).
// ---------------------------------------------------------------------------
__global__ __launch_bounds__(256) void zero_kernel(f32x4* __restrict__ p, int n4) {
  int i = blockIdx.x * blockDim.x + threadIdx.x;
  const int stride = gridDim.x * blockDim.x;
  const f32x4 z = {0.f, 0.f, 0.f, 0.f};
  for (; i < n4; i += stride) __builtin_nontemporal_store(z, &p[i]);
}

// ---------------------------------------------------------------------------
// Kernel 1: fused gating GEMM (fp64 accum) + threefry noise + fp64 softmax.
// Block = 256 threads = 4 waves; 16 rows/block; lane = expert.
// LDS x-reads are float4 broadcasts (ds_read_b128) -> 4x fewer LDS instrs.
// ---------------------------------------------------------------------------
#define RPB 16
__global__ __launch_bounds__(256) void gate_kernel(
    const float* __restrict__ x,   // (NROWS, 512)
    const float* __restrict__ Wt,  // (512, 64)
    float* __restrict__ gates) {   // (NROWS, 64)
  __shared__ float xs[RPB * DM];  // 32 KB
  const int e = threadIdx.x & 63;
  const int q = threadIdx.x >> 6;  // wave id 0..3
  const int row0 = blockIdx.x * RPB;

  // stage x tile (coalesced float4)
  const f32x4* src = (const f32x4*)(x + (size_t)row0 * DM);
  f32x4* dst = (f32x4*)xs;
  for (int i = threadIdx.x; i < RPB * (DM / 4); i += 256) dst[i] = src[i];
  __syncthreads();

  double acc0 = 0.0, acc1 = 0.0, acc2 = 0.0, acc3 = 0.0;
#pragma unroll 2
  for (int d = 0; d < DM; d += 4) {
    const f32x4 x0 = *(const f32x4*)&xs[(q + 0) * DM + d];
    const f32x4 x1 = *(const f32x4*)&xs[(q + 4) * DM + d];
    const f32x4 x2 = *(const f32x4*)&xs[(q + 8) * DM + d];
    const f32x4 x3 = *(const f32x4*)&xs[(q + 12) * DM + d];
#pragma unroll
    for (int k = 0; k < 4; ++k) {
      const double w = (double)Wt[(d + k) * NE + e];
      acc0 += (double)x0[k] * w;
      acc1 += (double)x1[k] * w;
      acc2 += (double)x2[k] * w;
      acc3 += (double)x3[k] * w;
    }
  }

  const double accs[4] = {acc0, acc1, acc2, acc3};
#pragma unroll
  for (int j = 0; j < 4; ++j) {
    const int row = row0 + q + 4 * j;
    float logit = (float)accs[j];
    float noised = logit + 0.015625f * jax_normal((uint32_t)(row * NE + e));
    // fp64 softmax across the 64 lanes (one expert per lane)
    double v = (double)noised;
    double m = v;
#pragma unroll
    for (int off = 32; off; off >>= 1) m = fmax(m, __shfl_xor(m, off, 64));
    double ex = exp(v - m);
    double s = ex;
#pragma unroll
    for (int off = 32; off; off >>= 1) s += __shfl_xor(s, off, 64);
    gates[(size_t)row * NE + e] = (float)(ex / s);
  }
}

// ---------------------------------------------------------------------------
// Kernel 2: one WAVE per (group, expert). 2048 candidates live in registers
// (32 per lane, statically indexed). Iterative top-32: per-lane unrolled
// scan + 6-step shfl_xor butterfly (max value, min index on ties — matches
// lax.top_k). No LDS, no barriers.
// ---------------------------------------------------------------------------
__global__ __launch_bounds__(64) void topk_kernel(
    const float* __restrict__ gates,  // (NROWS, 64)
    float* __restrict__ out) {        // combine ++ dispatch
  const int ge = blockIdx.x;  // 0..511
  const int g = ge >> 6;
  const int e = ge & 63;
  const int lane = threadIdx.x;

  // lane owns s = j*64 + lane
  float v[32];
#pragma unroll
  for (int j = 0; j < 32; ++j)
    v[j] = gates[((size_t)(g * GS + j * 64 + lane)) * NE + e];

  float my_v = 0.0f;
  int my_s = 0;

  for (int c = 0; c < CAP; ++c) {
    // per-lane argmax over 32 registers (ties -> smaller j, i.e. smaller s)
    float bv = -1.0f;  // gates are strictly positive
    int bj = 0;
#pragma unroll
    for (int j = 0; j < 32; ++j) {
      const bool better = v[j] > bv;
      bv = better ? v[j] : bv;
      bj = better ? j : bj;
    }
    int bs = bj * 64 + lane;
    // wave-wide reduce: max value, tie -> min s
#pragma unroll
    for (int off = 1; off < 64; off <<= 1) {
      const float ov = __shfl_xor(bv, off, 64);
      const int os = __shfl_xor(bs, off, 64);
      if (ov > bv || (ov == bv && os < bs)) { bv = ov; bs = os; }
    }
    // all lanes now agree on (bv, bs); owner lane removes it (static idx)
    const bool owner = (lane == (bs & 63));
    const int jj = bs >> 6;
#pragma unroll
    for (int j = 0; j < 32; ++j) v[j] = (owner && j == jj) ? -1.0f : v[j];
    if (lane == c) { my_v = bv; my_s = bs; }
  }

  float* combine = out;                   // (G,S,E,C)
  float* dispatch = out + COMBINE_ELEMS;  // (G,E,C,S)
  if (lane < CAP) {
    combine[(((size_t)(g * GS + my_s)) * NE + e) * CAP + lane] = my_v;
    dispatch[(((size_t)(g * NE + e)) * CAP + lane) * GS + my_s] = 1.0f;
  }
}

extern "C" void kernel_launch(void* const* d_in, const int* in_sizes, int n_in,
                              void* d_out, int out_size, void* d_ws,
                              size_t ws_size, hipStream_t stream) {
  (void)in_sizes; (void)n_in; (void)ws_size;
  const float* x = (const float*)d_in[0];   // (8,2048,512) f32
  const float* Wt = (const float*)d_in[1];  // (512,64) f32
  float* out = (float*)d_out;
  float* gates = (float*)d_ws;              // 16384*64 f32 = 4 MB scratch

  int n4 = out_size / 4;
  zero_kernel<<<2048, 256, 0, stream>>>((f32x4*)out, n4);
  gate_kernel<<<NROWS / RPB, 256, 0, stream>>>(x, Wt, gates);
  topk_kernel<<<NG * NE, 64, 0, stream>>>(gates, out);
}